// Round 20
// baseline (90.640 us; speedup 1.0000x reference)
//
#include <hip/hip_runtime.h>

// Problem: N=4, C=64, H=W=128, KS=3, dilations {1,3,5}
// x[4,64,128,128] f32, y[same], gen_w[1728,64], gen_b[1728],
// fuse_w[64,256,3,3], fuse_b[64] -> out[4,64,128,128] f32.

using f32x4 = __attribute__((ext_vector_type(4))) float;
using u32x4 = __attribute__((ext_vector_type(4))) unsigned;
using s16x8 = __attribute__((ext_vector_type(8))) short;

// Padded xp geometry: [plane][140 rows][144 cols], row = hh+5, col = ww+8.
#define XP_PS 20160        // plane stride in u32 (140*144)

// Workspace layout (float offsets)
#define OFF_WPK 0u         // gen_w A-frags bf16 [tap][tile12][ks2][lane][8] = 110592 bf16
#define OFF_FW3 55296u     // fuse_w A-frags bf16 [g][chunk][ks][rt][lane][8] = 147456 bf16
#define OFF_GBP 129024u    // gen_b fragment-order f32 [tap][tile12][row16]
#define OFF_XP  131072u    // x bf16-pairs u32, PADDED [n*32][140][144] = 2580480 u32
#define OFF_CATP 4325376u  // cat bf16-pairs u32 [n*96][16384]
// end 10616832 floats (~42.5 MB)

__device__ __forceinline__ unsigned short f2bf(float f) {
    unsigned u = __builtin_bit_cast(unsigned, f);
    u = (u + 0x7fffu + ((u >> 16) & 1u)) >> 16;   // RNE
    return (unsigned short)u;
}
__device__ __forceinline__ float bflo(unsigned p) {
    return __builtin_bit_cast(float, p << 16);
}
__device__ __forceinline__ float bfhi(unsigned p) {
    return __builtin_bit_cast(float, p & 0xffff0000u);
}

// ---- merged prep: blocks 0..53 wpk, 54..60 gb, 61..132 fw3, 133..2652 xp
__global__ void k_prep(const float* __restrict__ gen_w,
                       const float* __restrict__ gen_b,
                       const float* __restrict__ fuse_w,
                       const float* __restrict__ x,
                       float* __restrict__ ws) {
    int b = blockIdx.x;
    int t = threadIdx.x;
    if (b < 54) {                       // gen_w A-frags (16x16x32)
        int idx = b * 256 + t;
        if (idx >= 13824) return;
        unsigned short* wpk = (unsigned short*)(ws + OFF_WPK);
        int lane = idx & 63;
        int r = idx >> 6;
        int ks = r & 1; r >>= 1;
        int tile = r % 12, tap = r / 12;
        int comb = tile * 16 + (lane & 15);
        int cc0  = ks * 32 + (lane >> 4) * 8;
        const float* src = gen_w + (size_t)(comb * 9 + tap) * 64 + cc0;
        unsigned short v[8];
#pragma unroll
        for (int j = 0; j < 8; ++j) v[j] = f2bf(src[j]);
        *(s16x8*)(wpk + (size_t)idx * 8) = *(const s16x8*)v;
    } else if (b < 61) {                // gen_b fragment order
        int idx = (b - 54) * 256 + t;
        if (idx >= 1728) return;
        int row = idx & 15;
        int r = idx >> 4;
        int tile = r % 12, tap = r / 12;
        ws[OFF_GBP + idx] = gen_b[(tile * 16 + row) * 9 + tap];
    } else if (b < 133) {               // fuse_w A-frags (16x16x32)
        int idx = (b - 61) * 256 + t;
        if (idx >= 18432) return;
        unsigned short* fw3 = (unsigned short*)(ws + OFF_FW3);
        int lane = idx & 63;
        int f = idx >> 6;
        int rt = f & 3; f >>= 2;
        int ks = f & 1; f >>= 1;
        int chunk = f & 3;
        int g = f >> 2;
        int oc = rt * 16 + (lane & 15);
        int ic = chunk * 64 + ks * 32 + (lane >> 4) * 8;
        const float* src = fuse_w + (size_t)oc * 2304 + (size_t)ic * 9 + g;
        unsigned short v[8];
#pragma unroll
        for (int j = 0; j < 8; ++j) v[j] = f2bf(src[j * 9]);
        *(s16x8*)(fw3 + (size_t)idx * 8) = *(const s16x8*)v;
    } else {                            // x -> padded bf16-pair planes
        int idx = (b - 133) * 256 + t;  // 0..645119 (2520 blocks exactly)
        unsigned* xp = (unsigned*)(ws + OFF_XP);
        int plane = idx / 5040;         // 5040 u32x4 tasks per plane
        int rem   = idx % 5040;
        int row   = rem / 36;           // 0..139
        int c4    = rem % 36;           // 0..35 (u32x4 units)
        u32x4 v = (u32x4){0u, 0u, 0u, 0u};
        if (row >= 5 && row < 133 && c4 >= 2 && c4 < 34) {
            const float* sx = x + (size_t)(2 * plane) * 16384 +
                              (row - 5) * 128 + (c4 * 4 - 8);
            f32x4 v0 = *(const f32x4*)sx;
            f32x4 v1 = *(const f32x4*)(sx + 16384);
#pragma unroll
            for (int j = 0; j < 4; ++j)
                v[j] = (unsigned)f2bf(v0[j]) | ((unsigned)f2bf(v1[j]) << 16);
        }
        *(u32x4*)(xp + (size_t)plane * XP_PS + row * 144 + c4 * 4) = v;
    }
}

// XCD-contiguous decode for k_gen (1024 blocks)
__device__ __forceinline__ void decode_wu(int id, int& h, int& w0, int& n) {
    int wu = (id & 7) * 128 + (id >> 3);
    h = wu & 127;
    int sn = wu >> 7;
    w0 = (sn & 1) << 6;
    n = sn >> 1;
}

// MFMA kernel-generation + in-register depthwise apply (R19-exact).
__global__ __launch_bounds__(256, 4) void k_gen_mfma(
    const unsigned* __restrict__ xp, const float* __restrict__ y,
    const unsigned short* __restrict__ wpk, const float* __restrict__ gbp,
    unsigned* __restrict__ catp)
{
    __shared__ __align__(16) unsigned Yt[2048];

    int h, w0, n;
    decode_wu(blockIdx.x, h, w0, n);
    const int t = threadIdx.x;
    const int lane = t & 63;
    const int wv = t >> 6;
    const int q = lane >> 4, col = lane & 15;

    {
        const float* yb = y + ((size_t)n * 64) * 16384 + h * 128 + w0 + lane;
#pragma unroll
        for (int p = 0; p < 8; ++p) {
            int cp = wv * 8 + p;
            float a = yb[(size_t)(2 * cp) * 16384];
            float b = yb[(size_t)(2 * cp + 1) * 16384];
            unsigned v = (unsigned)f2bf(a) | ((unsigned)f2bf(b) << 16);
            Yt[(unsigned)(lane * 32 + cp) ^ (((unsigned)(lane & 7)) << 2)] = v;
        }
    }
    __syncthreads();

    s16x8 bfr[4][2];
#pragma unroll
    for (int ctp = 0; ctp < 4; ++ctp)
#pragma unroll
        for (int ks = 0; ks < 2; ++ks) {
            int px = ctp * 16 + col;
            unsigned word = ((unsigned)(px * 32 + ks * 16 + q * 4)) ^
                            (((unsigned)(px & 7)) << 2);
            bfr[ctp][ks] = *(const s16x8*)(Yt + word);
        }

    const int tile0 = wv * 3;
    const unsigned* xn = xp + (size_t)n * 32 * XP_PS;

    float acc[3][4][4];
#pragma unroll
    for (int rt = 0; rt < 3; ++rt)
#pragma unroll
        for (int ctp = 0; ctp < 4; ++ctp)
#pragma unroll
            for (int r = 0; r < 4; ++r) acc[rt][ctp][r] = 0.f;

#pragma unroll 1
    for (int tap = 0; tap < 9; ++tap) {
        const int ti = tap / 3, tj = tap % 3;
        const unsigned short* wp = wpk + ((size_t)(tap * 12 + tile0) * 2 * 64 + lane) * 8;
#pragma unroll
        for (int rt = 0; rt < 3; ++rt) {
            const int tile = tile0 + rt;
            const int bi = tile >> 2;
            const int d  = 2 * bi + 1;
            const int hh = h + (ti - 1) * d;
            const int cb = (tile & 3) * 16 + q * 4;

            f32x4 cinit = *(const f32x4*)(gbp + (size_t)(tap * 12 + tile) * 16 + q * 4);
            s16x8 a0 = *(const s16x8*)(wp + (size_t)(rt * 2 + 0) * 512);
            s16x8 a1 = *(const s16x8*)(wp + (size_t)(rt * 2 + 1) * 512);
#pragma unroll
            for (int ctp = 0; ctp < 4; ++ctp) {
                f32x4 kf = __builtin_amdgcn_mfma_f32_16x16x32_bf16(a0, bfr[ctp][0], cinit, 0, 0, 0);
                kf = __builtin_amdgcn_mfma_f32_16x16x32_bf16(a1, bfr[ctp][1], kf, 0, 0, 0);
                const int ww = w0 + ctp * 16 + col + (tj - 1) * d;
                const unsigned* xr = xn + (size_t)(cb >> 1) * XP_PS +
                                     (hh + 5) * 144 + (ww + 8);
                unsigned p0 = xr[0];
                unsigned p1 = xr[XP_PS];
                acc[rt][ctp][0] = fmaf(kf[0], bflo(p0), acc[rt][ctp][0]);
                acc[rt][ctp][1] = fmaf(kf[1], bfhi(p0), acc[rt][ctp][1]);
                acc[rt][ctp][2] = fmaf(kf[2], bflo(p1), acc[rt][ctp][2]);
                acc[rt][ctp][3] = fmaf(kf[3], bfhi(p1), acc[rt][ctp][3]);
            }
        }
    }

    unsigned* cb0 = catp + (size_t)n * 96 * 16384 + h * 128;
#pragma unroll
    for (int rt = 0; rt < 3; ++rt) {
        const int combr = (tile0 + rt) * 16 + q * 4;
#pragma unroll
        for (int ctp = 0; ctp < 4; ++ctp) {
            const int px = w0 + ctp * 16 + col;
            unsigned v0 = (unsigned)f2bf(acc[rt][ctp][0]) |
                          ((unsigned)f2bf(acc[rt][ctp][1]) << 16);
            unsigned v1 = (unsigned)f2bf(acc[rt][ctp][2]) |
                          ((unsigned)f2bf(acc[rt][ctp][3]) << 16);
            cb0[(size_t)((combr >> 1) + 0) * 16384 + px] = v0;
            cb0[(size_t)((combr >> 1) + 1) * 16384 + px] = v1;
        }
    }
}

// Fuse conv v11: 512-thread blocks, 8 waves = (ctp, ks) split-K-by-2.
// Same grid 512 / tile / staging; waves/CU 8 -> 16 for latency hiding.
// ks=1 partials reduced through Xt (aliased, 32KB) at the end.
// Prefetch issued AFTER the barrier so it isn't drained by it.
__global__ __launch_bounds__(512) void k_fuse_mfma(
    const unsigned* __restrict__ xp, const unsigned* __restrict__ catp,
    const unsigned short* __restrict__ fw3, const float* __restrict__ fuse_b,
    float* __restrict__ out)
{
    __shared__ __align__(16) unsigned Xt[4 * 32 * 68];  // 34.8 KB (R7 layout)

    const int id = blockIdx.x;
    const int xcd = id & 7;
    const int unit = id >> 3;          // 0..63
    const int h0 = unit << 1;
    const int n  = xcd >> 1;
    const int w0 = (xcd & 1) << 6;

    const int t = threadIdx.x;         // 0..511
    const int lane = t & 63;
    const int wv = t >> 6;             // 0..7
    const int ctp = wv >> 1;           // px tile 0..3
    const int ks  = wv & 1;            // K half
    const int col = lane & 15, q = lane >> 4;

    // staging decode: 2048 interior b128 tasks, 4 per thread
    int s_r[4], s_cp[4], s_li[4];
#pragma unroll
    for (int it = 0; it < 4; ++it) {
        int e = it * 512 + t;          // [r4][cp32][li16]
        s_r[it]  = e >> 9;
        s_cp[it] = (e >> 4) & 31;
        s_li[it] = e & 15;
    }
    // halo: 256 tasks [r4][cp32][side2]; threads t<256 take one each
    const bool hact = (t < 256);
    const int hr = t >> 6, hcp = (t >> 1) & 31, hside = t & 1;
    const int hpx = hside ? (w0 + 64) : (w0 - 1);
    const bool hok = hact && ((unsigned)hpx < 128u);

    const int bcol = ctp * 16 + col;
    const int m_kw[3] = { (bcol == 0) ? 64 : bcol - 1,
                          bcol,
                          (bcol == 63) ? 65 : bcol + 1 };

    f32x4 acc[2][4];                   // [row][rt]
#pragma unroll
    for (int row = 0; row < 2; ++row)
#pragma unroll
        for (int rt = 0; rt < 4; ++rt) acc[row][rt] = (f32x4){0.f, 0.f, 0.f, 0.f};

    const unsigned* csrc[4] = {
        nullptr,
        catp + (size_t)n * 96 * 16384,
        catp + ((size_t)n * 96 + 32) * 16384,
        catp + ((size_t)n * 96 + 64) * 16384 };

    // ---- prefetch chunk 0 from PADDED xp: unconditional loads ----
    u32x4 pf[4];
    unsigned pfh = 0u;
    {
        const unsigned* src0 = xp + (size_t)n * 32 * XP_PS;
#pragma unroll
        for (int it = 0; it < 4; ++it)
            pf[it] = *(const u32x4*)(src0 + (size_t)s_cp[it] * XP_PS +
                                     (h0 + 4 + s_r[it]) * 144 + 8 + w0 + s_li[it] * 4);
        if (hact)
            pfh = src0[(size_t)hcp * XP_PS + (h0 + 4 + hr) * 144 + 8 + hpx];
    }

#pragma unroll 1
    for (int chunk = 0; chunk < 4; ++chunk) {
        // ---- preload this chunk's first af (own ks); drained at barrier = ready
        s16x8 afc[4];
        {
            const unsigned short* ap =
                fw3 + ((size_t)(((chunk * 2 + ks) * 4) * 64 + lane)) * 8;   // g=0
#pragma unroll
            for (int rt = 0; rt < 4; ++rt)
                afc[rt] = *(const s16x8*)(ap + (size_t)rt * 512);
        }

        // ---- write staged regs to LDS ----
#pragma unroll
        for (int it = 0; it < 4; ++it)
            *(u32x4*)(Xt + (s_r[it] * 32 + s_cp[it]) * 68 + s_li[it] * 4) = pf[it];
        if (hact)
            Xt[(hr * 32 + hcp) * 68 + 64 + hside] = pfh;

        __syncthreads();

        // ---- issue next chunk's prefetch AFTER the barrier (rides under compute)
        if (chunk < 3) {
            const unsigned* src = csrc[chunk + 1];
#pragma unroll
            for (int it = 0; it < 4; ++it) {
                int hh = h0 - 1 + s_r[it];
                u32x4 v = (u32x4){0u, 0u, 0u, 0u};
                if ((unsigned)hh < 128u)
                    v = *(const u32x4*)(src + (size_t)s_cp[it] * 16384 + hh * 128 + w0 + s_li[it] * 4);
                pf[it] = v;
            }
            int hh = h0 - 1 + hr;
            unsigned v = 0u;
            if (hok && (unsigned)hh < 128u)
                v = src[(size_t)hcp * 16384 + hh * 128 + hpx];
            pfh = v;
        }

        // ---- compute: 9 taps (own ks), af software-pipelined 1 ahead ----
#pragma unroll
        for (int g = 0; g < 9; ++g) {
            const int kh = g / 3, kw = g % 3;

            s16x8 afn[4];
            if (g < 8) {
                const unsigned short* ap = fw3 +
                    ((size_t)(((((g + 1) * 4 + chunk) * 2 + ks) * 4) * 64 + lane)) * 8;
#pragma unroll
                for (int rt = 0; rt < 4; ++rt)
                    afn[rt] = *(const s16x8*)(ap + (size_t)rt * 512);
            }

            const int cpb = ks * 16 + q * 4;
            const int mm = m_kw[kw];
            s16x8 bf[2];
#pragma unroll
            for (int row = 0; row < 2; ++row) {
                const unsigned* bp = Xt + ((row + kh) * 32 + cpb) * 68 + mm;
                unsigned bb[4] = {bp[0], bp[68], bp[136], bp[204]};
                bf[row] = *(const s16x8*)bb;
            }
#pragma unroll
            for (int rt = 0; rt < 4; ++rt)
#pragma unroll
                for (int row = 0; row < 2; ++row)
                    acc[row][rt] = __builtin_amdgcn_mfma_f32_16x16x32_bf16(
                        afc[rt], bf[row], acc[row][rt], 0, 0, 0);

            if (g < 8) {
#pragma unroll
                for (int rt = 0; rt < 4; ++rt) afc[rt] = afn[rt];
            }
        }
        __syncthreads();
    }

    // ---- split-K reduction through Xt (aliased as f32; 32KB) ----
    float* red = (float*)Xt;
    if (ks == 1) {
#pragma unroll
        for (int row = 0; row < 2; ++row)
#pragma unroll
            for (int rt = 0; rt < 4; ++rt)
                *(f32x4*)(red + ((((ctp * 2 + row) * 4 + rt) * 64 + lane) << 2)) =
                    acc[row][rt];
    }
    __syncthreads();
    if (ks == 0) {
        const int px = w0 + ctp * 16 + col;
#pragma unroll
        for (int rt = 0; rt < 4; ++rt) {
            f32x4 fb = *(const f32x4*)(fuse_b + rt * 16 + q * 4);
#pragma unroll
            for (int row = 0; row < 2; ++row) {
                f32x4 s = acc[row][rt] +
                    *(const f32x4*)(red + ((((ctp * 2 + row) * 4 + rt) * 64 + lane) << 2));
#pragma unroll
                for (int r = 0; r < 4; ++r) {
                    int oc = rt * 16 + q * 4 + r;
                    out[((size_t)n * 64 + oc) * 16384 + (h0 + row) * 128 + px] =
                        s[r] + fb[r];
                }
            }
        }
    }
}

extern "C" void kernel_launch(void* const* d_in, const int* in_sizes, int n_in,
                              void* d_out, int out_size, void* d_ws, size_t ws_size,
                              hipStream_t stream) {
    const float* x      = (const float*)d_in[0];
    const float* y      = (const float*)d_in[1];
    const float* gen_w  = (const float*)d_in[2];
    const float* gen_b  = (const float*)d_in[3];
    const float* fuse_w = (const float*)d_in[4];
    const float* fuse_b = (const float*)d_in[5];
    float* out = (float*)d_out;
    float* ws  = (float*)d_ws;

    unsigned* xp   = (unsigned*)(ws + OFF_XP);
    unsigned* catp = (unsigned*)(ws + OFF_CATP);

    k_prep<<<dim3(2653), dim3(256), 0, stream>>>(gen_w, gen_b, fuse_w, x, ws);
    k_gen_mfma<<<dim3(1024), dim3(256), 0, stream>>>(
        xp, y, (const unsigned short*)(ws + OFF_WPK), ws + OFF_GBP, catp);
    k_fuse_mfma<<<dim3(512), dim3(512), 0, stream>>>(
        xp, catp, (const unsigned short*)(ws + OFF_FW3), fuse_b, out);
}

// Round 21
// 84.104 us; speedup vs baseline: 1.0777x; 1.0777x over previous
//
#include <hip/hip_runtime.h>

// Problem: N=4, C=64, H=W=128, KS=3, dilations {1,3,5}
// x[4,64,128,128] f32, y[same], gen_w[1728,64], gen_b[1728],
// fuse_w[64,256,3,3], fuse_b[64] -> out[4,64,128,128] f32.

using f32x4 = __attribute__((ext_vector_type(4))) float;
using u32x4 = __attribute__((ext_vector_type(4))) unsigned;
using s16x8 = __attribute__((ext_vector_type(8))) short;

// Padded xp geometry: [plane][140 rows][144 cols], row = hh+5, col = ww+8.
#define XP_PS 20160        // plane stride in u32 (140*144)

// Workspace layout (float offsets)
#define OFF_WPK 0u         // gen_w A-frags bf16 [tap][tile12][ks2][lane][8] = 110592 bf16
#define OFF_FW3 55296u     // fuse_w A-frags bf16 [g][chunk][ks][rt][lane][8] = 147456 bf16
#define OFF_GBP 129024u    // gen_b fragment-order f32 [tap][tile12][row16]
#define OFF_XP  131072u    // x bf16-pairs u32, PADDED [n*32][140][144] = 2580480 u32
#define OFF_CATP 4325376u  // cat bf16-pairs u32 [n*96][16384]
// end 10616832 floats (~42.5 MB)

__device__ __forceinline__ unsigned short f2bf(float f) {
    unsigned u = __builtin_bit_cast(unsigned, f);
    u = (u + 0x7fffu + ((u >> 16) & 1u)) >> 16;   // RNE
    return (unsigned short)u;
}
__device__ __forceinline__ float bflo(unsigned p) {
    return __builtin_bit_cast(float, p << 16);
}
__device__ __forceinline__ float bfhi(unsigned p) {
    return __builtin_bit_cast(float, p & 0xffff0000u);
}

// ---- merged prep: blocks 0..53 wpk, 54..60 gb, 61..132 fw3, 133..2652 xp
__global__ void k_prep(const float* __restrict__ gen_w,
                       const float* __restrict__ gen_b,
                       const float* __restrict__ fuse_w,
                       const float* __restrict__ x,
                       float* __restrict__ ws) {
    int b = blockIdx.x;
    int t = threadIdx.x;
    if (b < 54) {                       // gen_w A-frags (16x16x32)
        int idx = b * 256 + t;
        if (idx >= 13824) return;
        unsigned short* wpk = (unsigned short*)(ws + OFF_WPK);
        int lane = idx & 63;
        int r = idx >> 6;
        int ks = r & 1; r >>= 1;
        int tile = r % 12, tap = r / 12;
        int comb = tile * 16 + (lane & 15);
        int cc0  = ks * 32 + (lane >> 4) * 8;
        const float* src = gen_w + (size_t)(comb * 9 + tap) * 64 + cc0;
        unsigned short v[8];
#pragma unroll
        for (int j = 0; j < 8; ++j) v[j] = f2bf(src[j]);
        *(s16x8*)(wpk + (size_t)idx * 8) = *(const s16x8*)v;
    } else if (b < 61) {                // gen_b fragment order
        int idx = (b - 54) * 256 + t;
        if (idx >= 1728) return;
        int row = idx & 15;
        int r = idx >> 4;
        int tile = r % 12, tap = r / 12;
        ws[OFF_GBP + idx] = gen_b[(tile * 16 + row) * 9 + tap];
    } else if (b < 133) {               // fuse_w A-frags (16x16x32)
        int idx = (b - 61) * 256 + t;
        if (idx >= 18432) return;
        unsigned short* fw3 = (unsigned short*)(ws + OFF_FW3);
        int lane = idx & 63;
        int f = idx >> 6;
        int rt = f & 3; f >>= 2;
        int ks = f & 1; f >>= 1;
        int chunk = f & 3;
        int g = f >> 2;
        int oc = rt * 16 + (lane & 15);
        int ic = chunk * 64 + ks * 32 + (lane >> 4) * 8;
        const float* src = fuse_w + (size_t)oc * 2304 + (size_t)ic * 9 + g;
        unsigned short v[8];
#pragma unroll
        for (int j = 0; j < 8; ++j) v[j] = f2bf(src[j * 9]);
        *(s16x8*)(fw3 + (size_t)idx * 8) = *(const s16x8*)v;
    } else {                            // x -> padded bf16-pair planes
        int idx = (b - 133) * 256 + t;  // 0..645119 (2520 blocks exactly)
        unsigned* xp = (unsigned*)(ws + OFF_XP);
        int plane = idx / 5040;         // 5040 u32x4 tasks per plane
        int rem   = idx % 5040;
        int row   = rem / 36;           // 0..139
        int c4    = rem % 36;           // 0..35 (u32x4 units)
        u32x4 v = (u32x4){0u, 0u, 0u, 0u};
        if (row >= 5 && row < 133 && c4 >= 2 && c4 < 34) {
            const float* sx = x + (size_t)(2 * plane) * 16384 +
                              (row - 5) * 128 + (c4 * 4 - 8);
            f32x4 v0 = *(const f32x4*)sx;
            f32x4 v1 = *(const f32x4*)(sx + 16384);
#pragma unroll
            for (int j = 0; j < 4; ++j)
                v[j] = (unsigned)f2bf(v0[j]) | ((unsigned)f2bf(v1[j]) << 16);
        }
        *(u32x4*)(xp + (size_t)plane * XP_PS + row * 144 + c4 * 4) = v;
    }
}

// XCD-contiguous decode for k_gen (1024 blocks)
__device__ __forceinline__ void decode_wu(int id, int& h, int& w0, int& n) {
    int wu = (id & 7) * 128 + (id >> 3);
    h = wu & 127;
    int sn = wu >> 7;
    w0 = (sn & 1) << 6;
    n = sn >> 1;
}

// MFMA kernel-generation + in-register depthwise apply (R19-exact).
__global__ __launch_bounds__(256, 4) void k_gen_mfma(
    const unsigned* __restrict__ xp, const float* __restrict__ y,
    const unsigned short* __restrict__ wpk, const float* __restrict__ gbp,
    unsigned* __restrict__ catp)
{
    __shared__ __align__(16) unsigned Yt[2048];

    int h, w0, n;
    decode_wu(blockIdx.x, h, w0, n);
    const int t = threadIdx.x;
    const int lane = t & 63;
    const int wv = t >> 6;
    const int q = lane >> 4, col = lane & 15;

    {
        const float* yb = y + ((size_t)n * 64) * 16384 + h * 128 + w0 + lane;
#pragma unroll
        for (int p = 0; p < 8; ++p) {
            int cp = wv * 8 + p;
            float a = yb[(size_t)(2 * cp) * 16384];
            float b = yb[(size_t)(2 * cp + 1) * 16384];
            unsigned v = (unsigned)f2bf(a) | ((unsigned)f2bf(b) << 16);
            Yt[(unsigned)(lane * 32 + cp) ^ (((unsigned)(lane & 7)) << 2)] = v;
        }
    }
    __syncthreads();

    s16x8 bfr[4][2];
#pragma unroll
    for (int ctp = 0; ctp < 4; ++ctp)
#pragma unroll
        for (int ks = 0; ks < 2; ++ks) {
            int px = ctp * 16 + col;
            unsigned word = ((unsigned)(px * 32 + ks * 16 + q * 4)) ^
                            (((unsigned)(px & 7)) << 2);
            bfr[ctp][ks] = *(const s16x8*)(Yt + word);
        }

    const int tile0 = wv * 3;
    const unsigned* xn = xp + (size_t)n * 32 * XP_PS;

    float acc[3][4][4];
#pragma unroll
    for (int rt = 0; rt < 3; ++rt)
#pragma unroll
        for (int ctp = 0; ctp < 4; ++ctp)
#pragma unroll
            for (int r = 0; r < 4; ++r) acc[rt][ctp][r] = 0.f;

#pragma unroll 1
    for (int tap = 0; tap < 9; ++tap) {
        const int ti = tap / 3, tj = tap % 3;
        const unsigned short* wp = wpk + ((size_t)(tap * 12 + tile0) * 2 * 64 + lane) * 8;
#pragma unroll
        for (int rt = 0; rt < 3; ++rt) {
            const int tile = tile0 + rt;
            const int bi = tile >> 2;
            const int d  = 2 * bi + 1;
            const int hh = h + (ti - 1) * d;
            const int cb = (tile & 3) * 16 + q * 4;

            f32x4 cinit = *(const f32x4*)(gbp + (size_t)(tap * 12 + tile) * 16 + q * 4);
            s16x8 a0 = *(const s16x8*)(wp + (size_t)(rt * 2 + 0) * 512);
            s16x8 a1 = *(const s16x8*)(wp + (size_t)(rt * 2 + 1) * 512);
#pragma unroll
            for (int ctp = 0; ctp < 4; ++ctp) {
                f32x4 kf = __builtin_amdgcn_mfma_f32_16x16x32_bf16(a0, bfr[ctp][0], cinit, 0, 0, 0);
                kf = __builtin_amdgcn_mfma_f32_16x16x32_bf16(a1, bfr[ctp][1], kf, 0, 0, 0);
                const int ww = w0 + ctp * 16 + col + (tj - 1) * d;
                const unsigned* xr = xn + (size_t)(cb >> 1) * XP_PS +
                                     (hh + 5) * 144 + (ww + 8);
                unsigned p0 = xr[0];
                unsigned p1 = xr[XP_PS];
                acc[rt][ctp][0] = fmaf(kf[0], bflo(p0), acc[rt][ctp][0]);
                acc[rt][ctp][1] = fmaf(kf[1], bfhi(p0), acc[rt][ctp][1]);
                acc[rt][ctp][2] = fmaf(kf[2], bflo(p1), acc[rt][ctp][2]);
                acc[rt][ctp][3] = fmaf(kf[3], bfhi(p1), acc[rt][ctp][3]);
            }
        }
    }

    unsigned* cb0 = catp + (size_t)n * 96 * 16384 + h * 128;
#pragma unroll
    for (int rt = 0; rt < 3; ++rt) {
        const int combr = (tile0 + rt) * 16 + q * 4;
#pragma unroll
        for (int ctp = 0; ctp < 4; ++ctp) {
            const int px = w0 + ctp * 16 + col;
            unsigned v0 = (unsigned)f2bf(acc[rt][ctp][0]) |
                          ((unsigned)f2bf(acc[rt][ctp][1]) << 16);
            unsigned v1 = (unsigned)f2bf(acc[rt][ctp][2]) |
                          ((unsigned)f2bf(acc[rt][ctp][3]) << 16);
            cb0[(size_t)((combr >> 1) + 0) * 16384 + px] = v0;
            cb0[(size_t)((combr >> 1) + 1) * 16384 + px] = v1;
        }
    }
}

// Fuse conv v12: R19 structure with ONE change — next-chunk prefetch issues
// AFTER the mid-barrier, so the barrier's vmcnt(0) drain doesn't serialize it;
// the loads ride under the 18-step compute instead.
__global__ __launch_bounds__(256) void k_fuse_mfma(
    const unsigned* __restrict__ xp, const unsigned* __restrict__ catp,
    const unsigned short* __restrict__ fw3, const float* __restrict__ fuse_b,
    float* __restrict__ out)
{
    __shared__ __align__(16) unsigned Xt[4 * 32 * 68];  // 34.8 KB (R7 layout)

    const int id = blockIdx.x;
    const int xcd = id & 7;
    const int unit = id >> 3;          // 0..63
    const int h0 = unit << 1;
    const int n  = xcd >> 1;
    const int w0 = (xcd & 1) << 6;

    const int t = threadIdx.x;
    const int lane = t & 63;
    const int ctp = t >> 6;            // wave-uniform px tile
    const int col = lane & 15, q = lane >> 4;

    int s_r[8], s_cp[8], s_li[8];
#pragma unroll
    for (int it = 0; it < 8; ++it) {
        int e = it * 256 + t;          // 2048 tasks: [r4][cp32][li16]
        s_r[it]  = e >> 9;
        s_cp[it] = (e >> 4) & 31;
        s_li[it] = e & 15;
    }
    const int hr = t >> 6, hcp = (t >> 1) & 31, hside = t & 1;
    const int hpx = hside ? (w0 + 64) : (w0 - 1);
    const bool hok = ((unsigned)hpx < 128u);

    const int bcol = ctp * 16 + col;
    const int m_kw[3] = { (bcol == 0) ? 64 : bcol - 1,
                          bcol,
                          (bcol == 63) ? 65 : bcol + 1 };

    f32x4 acc[2][4];                   // [row][rt]
#pragma unroll
    for (int row = 0; row < 2; ++row)
#pragma unroll
        for (int rt = 0; rt < 4; ++rt) acc[row][rt] = (f32x4){0.f, 0.f, 0.f, 0.f};

    const unsigned* csrc[4] = {
        nullptr,
        catp + (size_t)n * 96 * 16384,
        catp + ((size_t)n * 96 + 32) * 16384,
        catp + ((size_t)n * 96 + 64) * 16384 };

    // ---- prefetch chunk 0 from PADDED xp: unconditional loads ----
    u32x4 pf[8];
    unsigned pfh;
    {
        const unsigned* src0 = xp + (size_t)n * 32 * XP_PS;
#pragma unroll
        for (int it = 0; it < 8; ++it)
            pf[it] = *(const u32x4*)(src0 + (size_t)s_cp[it] * XP_PS +
                                     (h0 + 4 + s_r[it]) * 144 + 8 + w0 + s_li[it] * 4);
        pfh = src0[(size_t)hcp * XP_PS + (h0 + 4 + hr) * 144 + 8 + hpx];
    }

#pragma unroll 1
    for (int chunk = 0; chunk < 4; ++chunk) {
        // ---- preload this chunk's first af (drained at barrier = ready) ----
        s16x8 afc[4];
        {
            const unsigned short* ap =
                fw3 + ((size_t)(((chunk * 2 + 0) * 4) * 64 + lane)) * 8;  // g=0,ks=0
#pragma unroll
            for (int rt = 0; rt < 4; ++rt)
                afc[rt] = *(const s16x8*)(ap + (size_t)rt * 512);
        }

        // ---- write staged regs to LDS ----
#pragma unroll
        for (int it = 0; it < 8; ++it)
            *(u32x4*)(Xt + (s_r[it] * 32 + s_cp[it]) * 68 + s_li[it] * 4) = pf[it];
        Xt[(hr * 32 + hcp) * 68 + 64 + hside] = pfh;

        __syncthreads();

        // ---- issue next chunk's prefetch AFTER the barrier: rides under
        //      compute; drained only at the end-of-chunk barrier ----
        if (chunk < 3) {
            const unsigned* src = csrc[chunk + 1];
#pragma unroll
            for (int it = 0; it < 8; ++it) {
                int hh = h0 - 1 + s_r[it];
                u32x4 v = (u32x4){0u, 0u, 0u, 0u};
                if ((unsigned)hh < 128u)
                    v = *(const u32x4*)(src + (size_t)s_cp[it] * 16384 + hh * 128 + w0 + s_li[it] * 4);
                pf[it] = v;
            }
            int hh = h0 - 1 + hr;
            unsigned v = 0u;
            if (hok && (unsigned)hh < 128u)
                v = src[(size_t)hcp * 16384 + hh * 128 + hpx];
            pfh = v;
        }

        // ---- compute: 18 (g,ks) steps, af software-pipelined 1 ahead ----
#pragma unroll
        for (int i = 0; i < 18; ++i) {
            const int g = i >> 1, ks = i & 1;
            const int kh = g / 3, kw = g % 3;

            s16x8 afn[4];
            if (i < 17) {
                const int g2 = (i + 1) >> 1, ks2 = (i + 1) & 1;
                const unsigned short* ap = fw3 +
                    ((size_t)((((g2 * 4 + chunk) * 2 + ks2) * 4) * 64 + lane)) * 8;
#pragma unroll
                for (int rt = 0; rt < 4; ++rt)
                    afn[rt] = *(const s16x8*)(ap + (size_t)rt * 512);
            }

            const int cpb = ks * 16 + q * 4;
            const int mm = m_kw[kw];
            s16x8 bf[2];
#pragma unroll
            for (int row = 0; row < 2; ++row) {
                const unsigned* bp = Xt + ((row + kh) * 32 + cpb) * 68 + mm;
                unsigned bb[4] = {bp[0], bp[68], bp[136], bp[204]};
                bf[row] = *(const s16x8*)bb;
            }
#pragma unroll
            for (int rt = 0; rt < 4; ++rt)
#pragma unroll
                for (int row = 0; row < 2; ++row)
                    acc[row][rt] = __builtin_amdgcn_mfma_f32_16x16x32_bf16(
                        afc[rt], bf[row], acc[row][rt], 0, 0, 0);

            if (i < 17) {
#pragma unroll
                for (int rt = 0; rt < 4; ++rt) afc[rt] = afn[rt];
            }
        }
        __syncthreads();
    }

    const int px = w0 + ctp * 16 + col;
#pragma unroll
    for (int rt = 0; rt < 4; ++rt) {
        f32x4 fb = *(const f32x4*)(fuse_b + rt * 16 + q * 4);
#pragma unroll
        for (int row = 0; row < 2; ++row)
#pragma unroll
            for (int r = 0; r < 4; ++r) {
                int oc = rt * 16 + q * 4 + r;
                out[((size_t)n * 64 + oc) * 16384 + (h0 + row) * 128 + px] =
                    acc[row][rt][r] + fb[r];
            }
    }
}

extern "C" void kernel_launch(void* const* d_in, const int* in_sizes, int n_in,
                              void* d_out, int out_size, void* d_ws, size_t ws_size,
                              hipStream_t stream) {
    const float* x      = (const float*)d_in[0];
    const float* y      = (const float*)d_in[1];
    const float* gen_w  = (const float*)d_in[2];
    const float* gen_b  = (const float*)d_in[3];
    const float* fuse_w = (const float*)d_in[4];
    const float* fuse_b = (const float*)d_in[5];
    float* out = (float*)d_out;
    float* ws  = (float*)d_ws;

    unsigned* xp   = (unsigned*)(ws + OFF_XP);
    unsigned* catp = (unsigned*)(ws + OFF_CATP);

    k_prep<<<dim3(2653), dim3(256), 0, stream>>>(gen_w, gen_b, fuse_w, x, ws);
    k_gen_mfma<<<dim3(1024), dim3(256), 0, stream>>>(
        xp, y, (const unsigned short*)(ws + OFF_WPK), ws + OFF_GBP, catp);
    k_fuse_mfma<<<dim3(512), dim3(256), 0, stream>>>(
        xp, catp, (const unsigned short*)(ws + OFF_FW3), fuse_b, out);
}

// Round 22
// 82.678 us; speedup vs baseline: 1.0963x; 1.0172x over previous
//
#include <hip/hip_runtime.h>

// Problem: N=4, C=64, H=W=128, KS=3, dilations {1,3,5}
// x[4,64,128,128] f32, y[same], gen_w[1728,64], gen_b[1728],
// fuse_w[64,256,3,3], fuse_b[64] -> out[4,64,128,128] f32.

using f32x4 = __attribute__((ext_vector_type(4))) float;
using u32x4 = __attribute__((ext_vector_type(4))) unsigned;
using s16x8 = __attribute__((ext_vector_type(8))) short;

// Padded xp geometry: [plane][140 rows][144 cols], row = hh+5, col = ww+8.
#define XP_PS 20160        // plane stride in u32 (140*144)

// Workspace layout (float offsets)
#define OFF_WPK 0u         // gen_w A-frags bf16 [tap][tile12][ks2][lane][8] = 110592 bf16
#define OFF_FW3 55296u     // fuse_w A-frags bf16 [g][chunk][ks][rt][lane][8] = 147456 bf16
#define OFF_GBP 129024u    // gen_b fragment-order f32 [tap][tile12][row16]
#define OFF_XP  131072u    // x bf16-pairs u32, PADDED [n*32][140][144] = 2580480 u32
#define OFF_CATP 4325376u  // cat bf16-pairs u32 [n*96][16384]
// end 10616832 floats (~42.5 MB)

__device__ __forceinline__ unsigned short f2bf(float f) {
    unsigned u = __builtin_bit_cast(unsigned, f);
    u = (u + 0x7fffu + ((u >> 16) & 1u)) >> 16;   // RNE
    return (unsigned short)u;
}
__device__ __forceinline__ float bflo(unsigned p) {
    return __builtin_bit_cast(float, p << 16);
}
__device__ __forceinline__ float bfhi(unsigned p) {
    return __builtin_bit_cast(float, p & 0xffff0000u);
}

// ---- merged prep: blocks 0..53 wpk, 54..60 gb, 61..132 fw3, 133..2652 xp
__global__ void k_prep(const float* __restrict__ gen_w,
                       const float* __restrict__ gen_b,
                       const float* __restrict__ fuse_w,
                       const float* __restrict__ x,
                       float* __restrict__ ws) {
    int b = blockIdx.x;
    int t = threadIdx.x;
    if (b < 54) {                       // gen_w A-frags (16x16x32)
        int idx = b * 256 + t;
        if (idx >= 13824) return;
        unsigned short* wpk = (unsigned short*)(ws + OFF_WPK);
        int lane = idx & 63;
        int r = idx >> 6;
        int ks = r & 1; r >>= 1;
        int tile = r % 12, tap = r / 12;
        int comb = tile * 16 + (lane & 15);
        int cc0  = ks * 32 + (lane >> 4) * 8;
        const float* src = gen_w + (size_t)(comb * 9 + tap) * 64 + cc0;
        unsigned short v[8];
#pragma unroll
        for (int j = 0; j < 8; ++j) v[j] = f2bf(src[j]);
        *(s16x8*)(wpk + (size_t)idx * 8) = *(const s16x8*)v;
    } else if (b < 61) {                // gen_b fragment order
        int idx = (b - 54) * 256 + t;
        if (idx >= 1728) return;
        int row = idx & 15;
        int r = idx >> 4;
        int tile = r % 12, tap = r / 12;
        ws[OFF_GBP + idx] = gen_b[(tile * 16 + row) * 9 + tap];
    } else if (b < 133) {               // fuse_w A-frags (16x16x32)
        int idx = (b - 61) * 256 + t;
        if (idx >= 18432) return;
        unsigned short* fw3 = (unsigned short*)(ws + OFF_FW3);
        int lane = idx & 63;
        int f = idx >> 6;
        int rt = f & 3; f >>= 2;
        int ks = f & 1; f >>= 1;
        int chunk = f & 3;
        int g = f >> 2;
        int oc = rt * 16 + (lane & 15);
        int ic = chunk * 64 + ks * 32 + (lane >> 4) * 8;
        const float* src = fuse_w + (size_t)oc * 2304 + (size_t)ic * 9 + g;
        unsigned short v[8];
#pragma unroll
        for (int j = 0; j < 8; ++j) v[j] = f2bf(src[j * 9]);
        *(s16x8*)(fw3 + (size_t)idx * 8) = *(const s16x8*)v;
    } else {                            // x -> padded bf16-pair planes
        int idx = (b - 133) * 256 + t;  // 0..645119 (2520 blocks exactly)
        unsigned* xp = (unsigned*)(ws + OFF_XP);
        int plane = idx / 5040;         // 5040 u32x4 tasks per plane
        int rem   = idx % 5040;
        int row   = rem / 36;           // 0..139
        int c4    = rem % 36;           // 0..35 (u32x4 units)
        u32x4 v = (u32x4){0u, 0u, 0u, 0u};
        if (row >= 5 && row < 133 && c4 >= 2 && c4 < 34) {
            const float* sx = x + (size_t)(2 * plane) * 16384 +
                              (row - 5) * 128 + (c4 * 4 - 8);
            f32x4 v0 = *(const f32x4*)sx;
            f32x4 v1 = *(const f32x4*)(sx + 16384);
#pragma unroll
            for (int j = 0; j < 4; ++j)
                v[j] = (unsigned)f2bf(v0[j]) | ((unsigned)f2bf(v1[j]) << 16);
        }
        *(u32x4*)(xp + (size_t)plane * XP_PS + row * 144 + c4 * 4) = v;
    }
}

// XCD-contiguous decode for k_gen (1024 blocks)
__device__ __forceinline__ void decode_wu(int id, int& h, int& w0, int& n) {
    int wu = (id & 7) * 128 + (id >> 3);
    h = wu & 127;
    int sn = wu >> 7;
    w0 = (sn & 1) << 6;
    n = sn >> 1;
}

// MFMA kernel-generation + in-register depthwise apply (R19-exact).
__global__ __launch_bounds__(256, 4) void k_gen_mfma(
    const unsigned* __restrict__ xp, const float* __restrict__ y,
    const unsigned short* __restrict__ wpk, const float* __restrict__ gbp,
    unsigned* __restrict__ catp)
{
    __shared__ __align__(16) unsigned Yt[2048];

    int h, w0, n;
    decode_wu(blockIdx.x, h, w0, n);
    const int t = threadIdx.x;
    const int lane = t & 63;
    const int wv = t >> 6;
    const int q = lane >> 4, col = lane & 15;

    {
        const float* yb = y + ((size_t)n * 64) * 16384 + h * 128 + w0 + lane;
#pragma unroll
        for (int p = 0; p < 8; ++p) {
            int cp = wv * 8 + p;
            float a = yb[(size_t)(2 * cp) * 16384];
            float b = yb[(size_t)(2 * cp + 1) * 16384];
            unsigned v = (unsigned)f2bf(a) | ((unsigned)f2bf(b) << 16);
            Yt[(unsigned)(lane * 32 + cp) ^ (((unsigned)(lane & 7)) << 2)] = v;
        }
    }
    __syncthreads();

    s16x8 bfr[4][2];
#pragma unroll
    for (int ctp = 0; ctp < 4; ++ctp)
#pragma unroll
        for (int ks = 0; ks < 2; ++ks) {
            int px = ctp * 16 + col;
            unsigned word = ((unsigned)(px * 32 + ks * 16 + q * 4)) ^
                            (((unsigned)(px & 7)) << 2);
            bfr[ctp][ks] = *(const s16x8*)(Yt + word);
        }

    const int tile0 = wv * 3;
    const unsigned* xn = xp + (size_t)n * 32 * XP_PS;

    float acc[3][4][4];
#pragma unroll
    for (int rt = 0; rt < 3; ++rt)
#pragma unroll
        for (int ctp = 0; ctp < 4; ++ctp)
#pragma unroll
            for (int r = 0; r < 4; ++r) acc[rt][ctp][r] = 0.f;

#pragma unroll 1
    for (int tap = 0; tap < 9; ++tap) {
        const int ti = tap / 3, tj = tap % 3;
        const unsigned short* wp = wpk + ((size_t)(tap * 12 + tile0) * 2 * 64 + lane) * 8;
#pragma unroll
        for (int rt = 0; rt < 3; ++rt) {
            const int tile = tile0 + rt;
            const int bi = tile >> 2;
            const int d  = 2 * bi + 1;
            const int hh = h + (ti - 1) * d;
            const int cb = (tile & 3) * 16 + q * 4;

            f32x4 cinit = *(const f32x4*)(gbp + (size_t)(tap * 12 + tile) * 16 + q * 4);
            s16x8 a0 = *(const s16x8*)(wp + (size_t)(rt * 2 + 0) * 512);
            s16x8 a1 = *(const s16x8*)(wp + (size_t)(rt * 2 + 1) * 512);
#pragma unroll
            for (int ctp = 0; ctp < 4; ++ctp) {
                f32x4 kf = __builtin_amdgcn_mfma_f32_16x16x32_bf16(a0, bfr[ctp][0], cinit, 0, 0, 0);
                kf = __builtin_amdgcn_mfma_f32_16x16x32_bf16(a1, bfr[ctp][1], kf, 0, 0, 0);
                const int ww = w0 + ctp * 16 + col + (tj - 1) * d;
                const unsigned* xr = xn + (size_t)(cb >> 1) * XP_PS +
                                     (hh + 5) * 144 + (ww + 8);
                unsigned p0 = xr[0];
                unsigned p1 = xr[XP_PS];
                acc[rt][ctp][0] = fmaf(kf[0], bflo(p0), acc[rt][ctp][0]);
                acc[rt][ctp][1] = fmaf(kf[1], bfhi(p0), acc[rt][ctp][1]);
                acc[rt][ctp][2] = fmaf(kf[2], bflo(p1), acc[rt][ctp][2]);
                acc[rt][ctp][3] = fmaf(kf[3], bfhi(p1), acc[rt][ctp][3]);
            }
        }
    }

    unsigned* cb0 = catp + (size_t)n * 96 * 16384 + h * 128;
#pragma unroll
    for (int rt = 0; rt < 3; ++rt) {
        const int combr = (tile0 + rt) * 16 + q * 4;
#pragma unroll
        for (int ctp = 0; ctp < 4; ++ctp) {
            const int px = w0 + ctp * 16 + col;
            unsigned v0 = (unsigned)f2bf(acc[rt][ctp][0]) |
                          ((unsigned)f2bf(acc[rt][ctp][1]) << 16);
            unsigned v1 = (unsigned)f2bf(acc[rt][ctp][2]) |
                          ((unsigned)f2bf(acc[rt][ctp][3]) << 16);
            cb0[(size_t)((combr >> 1) + 0) * 16384 + px] = v0;
            cb0[(size_t)((combr >> 1) + 1) * 16384 + px] = v1;
        }
    }
}

// Fuse conv v13: R21 structure + 2-deep af pipeline (af for steps i+1 AND
// i+2 in flight -> ~300+cy of L2 cover vs ~150cy at 1-deep).
__global__ __launch_bounds__(256) void k_fuse_mfma(
    const unsigned* __restrict__ xp, const unsigned* __restrict__ catp,
    const unsigned short* __restrict__ fw3, const float* __restrict__ fuse_b,
    float* __restrict__ out)
{
    __shared__ __align__(16) unsigned Xt[4 * 32 * 68];  // 34.8 KB (R7 layout)

    const int id = blockIdx.x;
    const int xcd = id & 7;
    const int unit = id >> 3;          // 0..63
    const int h0 = unit << 1;
    const int n  = xcd >> 1;
    const int w0 = (xcd & 1) << 6;

    const int t = threadIdx.x;
    const int lane = t & 63;
    const int ctp = t >> 6;            // wave-uniform px tile
    const int col = lane & 15, q = lane >> 4;

    int s_r[8], s_cp[8], s_li[8];
#pragma unroll
    for (int it = 0; it < 8; ++it) {
        int e = it * 256 + t;          // 2048 tasks: [r4][cp32][li16]
        s_r[it]  = e >> 9;
        s_cp[it] = (e >> 4) & 31;
        s_li[it] = e & 15;
    }
    const int hr = t >> 6, hcp = (t >> 1) & 31, hside = t & 1;
    const int hpx = hside ? (w0 + 64) : (w0 - 1);
    const bool hok = ((unsigned)hpx < 128u);

    const int bcol = ctp * 16 + col;
    const int m_kw[3] = { (bcol == 0) ? 64 : bcol - 1,
                          bcol,
                          (bcol == 63) ? 65 : bcol + 1 };

    f32x4 acc[2][4];                   // [row][rt]
#pragma unroll
    for (int row = 0; row < 2; ++row)
#pragma unroll
        for (int rt = 0; rt < 4; ++rt) acc[row][rt] = (f32x4){0.f, 0.f, 0.f, 0.f};

    const unsigned* csrc[4] = {
        nullptr,
        catp + (size_t)n * 96 * 16384,
        catp + ((size_t)n * 96 + 32) * 16384,
        catp + ((size_t)n * 96 + 64) * 16384 };

    // helper: af pointer for step index i (= g*2+ks) of a chunk
    auto afp = [&](int chunk, int i) -> const unsigned short* {
        const int g = i >> 1, ks = i & 1;
        return fw3 + ((size_t)((((g * 4 + chunk) * 2 + ks) * 4) * 64 + lane)) * 8;
    };

    // ---- prefetch chunk 0 from PADDED xp: unconditional loads ----
    u32x4 pf[8];
    unsigned pfh;
    {
        const unsigned* src0 = xp + (size_t)n * 32 * XP_PS;
#pragma unroll
        for (int it = 0; it < 8; ++it)
            pf[it] = *(const u32x4*)(src0 + (size_t)s_cp[it] * XP_PS +
                                     (h0 + 4 + s_r[it]) * 144 + 8 + w0 + s_li[it] * 4);
        pfh = src0[(size_t)hcp * XP_PS + (h0 + 4 + hr) * 144 + 8 + hpx];
    }

#pragma unroll 1
    for (int chunk = 0; chunk < 4; ++chunk) {
        // ---- preload af for steps 0 and 1 (drained at barrier = ready) ----
        s16x8 afc[4], afn1[4];
        {
            const unsigned short* ap0 = afp(chunk, 0);
            const unsigned short* ap1 = afp(chunk, 1);
#pragma unroll
            for (int rt = 0; rt < 4; ++rt) {
                afc[rt]  = *(const s16x8*)(ap0 + (size_t)rt * 512);
                afn1[rt] = *(const s16x8*)(ap1 + (size_t)rt * 512);
            }
        }

        // ---- write staged regs to LDS ----
#pragma unroll
        for (int it = 0; it < 8; ++it)
            *(u32x4*)(Xt + (s_r[it] * 32 + s_cp[it]) * 68 + s_li[it] * 4) = pf[it];
        Xt[(hr * 32 + hcp) * 68 + 64 + hside] = pfh;

        __syncthreads();

        // ---- issue next chunk's prefetch AFTER the barrier ----
        if (chunk < 3) {
            const unsigned* src = csrc[chunk + 1];
#pragma unroll
            for (int it = 0; it < 8; ++it) {
                int hh = h0 - 1 + s_r[it];
                u32x4 v = (u32x4){0u, 0u, 0u, 0u};
                if ((unsigned)hh < 128u)
                    v = *(const u32x4*)(src + (size_t)s_cp[it] * 16384 + hh * 128 + w0 + s_li[it] * 4);
                pf[it] = v;
            }
            int hh = h0 - 1 + hr;
            unsigned v = 0u;
            if (hok && (unsigned)hh < 128u)
                v = src[(size_t)hcp * 16384 + hh * 128 + hpx];
            pfh = v;
        }

        // ---- compute: 18 (g,ks) steps; af pipelined 2 deep ----
#pragma unroll
        for (int i = 0; i < 18; ++i) {
            const int g = i >> 1, ks = i & 1;
            const int kh = g / 3, kw = g % 3;

            s16x8 afn2[4];
            if (i < 16) {
                const unsigned short* ap = afp(chunk, i + 2);
#pragma unroll
                for (int rt = 0; rt < 4; ++rt)
                    afn2[rt] = *(const s16x8*)(ap + (size_t)rt * 512);
            }

            const int cpb = ks * 16 + q * 4;
            const int mm = m_kw[kw];
            s16x8 bf[2];
#pragma unroll
            for (int row = 0; row < 2; ++row) {
                const unsigned* bp = Xt + ((row + kh) * 32 + cpb) * 68 + mm;
                unsigned bb[4] = {bp[0], bp[68], bp[136], bp[204]};
                bf[row] = *(const s16x8*)bb;
            }
#pragma unroll
            for (int rt = 0; rt < 4; ++rt)
#pragma unroll
                for (int row = 0; row < 2; ++row)
                    acc[row][rt] = __builtin_amdgcn_mfma_f32_16x16x32_bf16(
                        afc[rt], bf[row], acc[row][rt], 0, 0, 0);

#pragma unroll
            for (int rt = 0; rt < 4; ++rt) {
                afc[rt] = afn1[rt];
                if (i < 16) afn1[rt] = afn2[rt];
            }
        }
        __syncthreads();
    }

    const int px = w0 + ctp * 16 + col;
#pragma unroll
    for (int rt = 0; rt < 4; ++rt) {
        f32x4 fb = *(const f32x4*)(fuse_b + rt * 16 + q * 4);
#pragma unroll
        for (int row = 0; row < 2; ++row)
#pragma unroll
            for (int r = 0; r < 4; ++r) {
                int oc = rt * 16 + q * 4 + r;
                out[((size_t)n * 64 + oc) * 16384 + (h0 + row) * 128 + px] =
                    acc[row][rt][r] + fb[r];
            }
    }
}

extern "C" void kernel_launch(void* const* d_in, const int* in_sizes, int n_in,
                              void* d_out, int out_size, void* d_ws, size_t ws_size,
                              hipStream_t stream) {
    const float* x      = (const float*)d_in[0];
    const float* y      = (const float*)d_in[1];
    const float* gen_w  = (const float*)d_in[2];
    const float* gen_b  = (const float*)d_in[3];
    const float* fuse_w = (const float*)d_in[4];
    const float* fuse_b = (const float*)d_in[5];
    float* out = (float*)d_out;
    float* ws  = (float*)d_ws;

    unsigned* xp   = (unsigned*)(ws + OFF_XP);
    unsigned* catp = (unsigned*)(ws + OFF_CATP);

    k_prep<<<dim3(2653), dim3(256), 0, stream>>>(gen_w, gen_b, fuse_w, x, ws);
    k_gen_mfma<<<dim3(1024), dim3(256), 0, stream>>>(
        xp, y, (const unsigned short*)(ws + OFF_WPK), ws + OFF_GBP, catp);
    k_fuse_mfma<<<dim3(512), dim3(256), 0, stream>>>(
        xp, catp, (const unsigned short*)(ws + OFF_FW3), fuse_b, out);
}

// Round 23
// 79.042 us; speedup vs baseline: 1.1467x; 1.0460x over previous
//
#include <hip/hip_runtime.h>

// Problem: N=4, C=64, H=W=128, KS=3, dilations {1,3,5}
// x[4,64,128,128] f32, y[same], gen_w[1728,64], gen_b[1728],
// fuse_w[64,256,3,3], fuse_b[64] -> out[4,64,128,128] f32.

using f32x4 = __attribute__((ext_vector_type(4))) float;
using u32x4 = __attribute__((ext_vector_type(4))) unsigned;
using s16x8 = __attribute__((ext_vector_type(8))) short;

// Padded xp geometry: [plane][140 rows][144 cols], row = hh+5, col = ww+8.
#define XP_PS 20160        // plane stride in u32 (140*144)

// Workspace layout (float offsets)
#define OFF_WPK 0u         // gen_w A-frags bf16 [tap][tile12][ks2][lane][8] = 110592 bf16
#define OFF_FW3 55296u     // fuse_w A-frags bf16 [g][chunk][ks][rt][lane][8] = 147456 bf16
#define OFF_GBP 129024u    // gen_b fragment-order f32 [tap][tile12][row16]
#define OFF_XP  131072u    // x bf16-pairs u32, PADDED [n*32][140][144] = 2580480 u32
#define OFF_CATP 4325376u  // cat bf16-pairs u32 [n*96][16384]
// end 10616832 floats (~42.5 MB)

__device__ __forceinline__ unsigned short f2bf(float f) {
    unsigned u = __builtin_bit_cast(unsigned, f);
    u = (u + 0x7fffu + ((u >> 16) & 1u)) >> 16;   // RNE
    return (unsigned short)u;
}
__device__ __forceinline__ float bflo(unsigned p) {
    return __builtin_bit_cast(float, p << 16);
}
__device__ __forceinline__ float bfhi(unsigned p) {
    return __builtin_bit_cast(float, p & 0xffff0000u);
}

// ---- merged prep: blocks 0..53 wpk, 54..60 gb, 61..132 fw3, 133..2652 xp
__global__ void k_prep(const float* __restrict__ gen_w,
                       const float* __restrict__ gen_b,
                       const float* __restrict__ fuse_w,
                       const float* __restrict__ x,
                       float* __restrict__ ws) {
    int b = blockIdx.x;
    int t = threadIdx.x;
    if (b < 54) {                       // gen_w A-frags (16x16x32)
        int idx = b * 256 + t;
        if (idx >= 13824) return;
        unsigned short* wpk = (unsigned short*)(ws + OFF_WPK);
        int lane = idx & 63;
        int r = idx >> 6;
        int ks = r & 1; r >>= 1;
        int tile = r % 12, tap = r / 12;
        int comb = tile * 16 + (lane & 15);
        int cc0  = ks * 32 + (lane >> 4) * 8;
        const float* src = gen_w + (size_t)(comb * 9 + tap) * 64 + cc0;
        unsigned short v[8];
#pragma unroll
        for (int j = 0; j < 8; ++j) v[j] = f2bf(src[j]);
        *(s16x8*)(wpk + (size_t)idx * 8) = *(const s16x8*)v;
    } else if (b < 61) {                // gen_b fragment order
        int idx = (b - 54) * 256 + t;
        if (idx >= 1728) return;
        int row = idx & 15;
        int r = idx >> 4;
        int tile = r % 12, tap = r / 12;
        ws[OFF_GBP + idx] = gen_b[(tile * 16 + row) * 9 + tap];
    } else if (b < 133) {               // fuse_w A-frags (16x16x32)
        int idx = (b - 61) * 256 + t;
        if (idx >= 18432) return;
        unsigned short* fw3 = (unsigned short*)(ws + OFF_FW3);
        int lane = idx & 63;
        int f = idx >> 6;
        int rt = f & 3; f >>= 2;
        int ks = f & 1; f >>= 1;
        int chunk = f & 3;
        int g = f >> 2;
        int oc = rt * 16 + (lane & 15);
        int ic = chunk * 64 + ks * 32 + (lane >> 4) * 8;
        const float* src = fuse_w + (size_t)oc * 2304 + (size_t)ic * 9 + g;
        unsigned short v[8];
#pragma unroll
        for (int j = 0; j < 8; ++j) v[j] = f2bf(src[j * 9]);
        *(s16x8*)(fw3 + (size_t)idx * 8) = *(const s16x8*)v;
    } else {                            // x -> padded bf16-pair planes
        int idx = (b - 133) * 256 + t;  // 0..645119 (2520 blocks exactly)
        unsigned* xp = (unsigned*)(ws + OFF_XP);
        int plane = idx / 5040;         // 5040 u32x4 tasks per plane
        int rem   = idx % 5040;
        int row   = rem / 36;           // 0..139
        int c4    = rem % 36;           // 0..35 (u32x4 units)
        u32x4 v = (u32x4){0u, 0u, 0u, 0u};
        if (row >= 5 && row < 133 && c4 >= 2 && c4 < 34) {
            const float* sx = x + (size_t)(2 * plane) * 16384 +
                              (row - 5) * 128 + (c4 * 4 - 8);
            f32x4 v0 = *(const f32x4*)sx;
            f32x4 v1 = *(const f32x4*)(sx + 16384);
#pragma unroll
            for (int j = 0; j < 4; ++j)
                v[j] = (unsigned)f2bf(v0[j]) | ((unsigned)f2bf(v1[j]) << 16);
        }
        *(u32x4*)(xp + (size_t)plane * XP_PS + row * 144 + c4 * 4) = v;
    }
}

// XCD-contiguous decode for k_gen (1024 blocks)
__device__ __forceinline__ void decode_wu(int id, int& h, int& w0, int& n) {
    int wu = (id & 7) * 128 + (id >> 3);
    h = wu & 127;
    int sn = wu >> 7;
    w0 = (sn & 1) << 6;
    n = sn >> 1;
}

// MFMA kernel-generation + in-register depthwise apply (R19-exact).
__global__ __launch_bounds__(256, 4) void k_gen_mfma(
    const unsigned* __restrict__ xp, const float* __restrict__ y,
    const unsigned short* __restrict__ wpk, const float* __restrict__ gbp,
    unsigned* __restrict__ catp)
{
    __shared__ __align__(16) unsigned Yt[2048];

    int h, w0, n;
    decode_wu(blockIdx.x, h, w0, n);
    const int t = threadIdx.x;
    const int lane = t & 63;
    const int wv = t >> 6;
    const int q = lane >> 4, col = lane & 15;

    {
        const float* yb = y + ((size_t)n * 64) * 16384 + h * 128 + w0 + lane;
#pragma unroll
        for (int p = 0; p < 8; ++p) {
            int cp = wv * 8 + p;
            float a = yb[(size_t)(2 * cp) * 16384];
            float b = yb[(size_t)(2 * cp + 1) * 16384];
            unsigned v = (unsigned)f2bf(a) | ((unsigned)f2bf(b) << 16);
            Yt[(unsigned)(lane * 32 + cp) ^ (((unsigned)(lane & 7)) << 2)] = v;
        }
    }
    __syncthreads();

    s16x8 bfr[4][2];
#pragma unroll
    for (int ctp = 0; ctp < 4; ++ctp)
#pragma unroll
        for (int ks = 0; ks < 2; ++ks) {
            int px = ctp * 16 + col;
            unsigned word = ((unsigned)(px * 32 + ks * 16 + q * 4)) ^
                            (((unsigned)(px & 7)) << 2);
            bfr[ctp][ks] = *(const s16x8*)(Yt + word);
        }

    const int tile0 = wv * 3;
    const unsigned* xn = xp + (size_t)n * 32 * XP_PS;

    float acc[3][4][4];
#pragma unroll
    for (int rt = 0; rt < 3; ++rt)
#pragma unroll
        for (int ctp = 0; ctp < 4; ++ctp)
#pragma unroll
            for (int r = 0; r < 4; ++r) acc[rt][ctp][r] = 0.f;

#pragma unroll 1
    for (int tap = 0; tap < 9; ++tap) {
        const int ti = tap / 3, tj = tap % 3;
        const unsigned short* wp = wpk + ((size_t)(tap * 12 + tile0) * 2 * 64 + lane) * 8;
#pragma unroll
        for (int rt = 0; rt < 3; ++rt) {
            const int tile = tile0 + rt;
            const int bi = tile >> 2;
            const int d  = 2 * bi + 1;
            const int hh = h + (ti - 1) * d;
            const int cb = (tile & 3) * 16 + q * 4;

            f32x4 cinit = *(const f32x4*)(gbp + (size_t)(tap * 12 + tile) * 16 + q * 4);
            s16x8 a0 = *(const s16x8*)(wp + (size_t)(rt * 2 + 0) * 512);
            s16x8 a1 = *(const s16x8*)(wp + (size_t)(rt * 2 + 1) * 512);
#pragma unroll
            for (int ctp = 0; ctp < 4; ++ctp) {
                f32x4 kf = __builtin_amdgcn_mfma_f32_16x16x32_bf16(a0, bfr[ctp][0], cinit, 0, 0, 0);
                kf = __builtin_amdgcn_mfma_f32_16x16x32_bf16(a1, bfr[ctp][1], kf, 0, 0, 0);
                const int ww = w0 + ctp * 16 + col + (tj - 1) * d;
                const unsigned* xr = xn + (size_t)(cb >> 1) * XP_PS +
                                     (hh + 5) * 144 + (ww + 8);
                unsigned p0 = xr[0];
                unsigned p1 = xr[XP_PS];
                acc[rt][ctp][0] = fmaf(kf[0], bflo(p0), acc[rt][ctp][0]);
                acc[rt][ctp][1] = fmaf(kf[1], bfhi(p0), acc[rt][ctp][1]);
                acc[rt][ctp][2] = fmaf(kf[2], bflo(p1), acc[rt][ctp][2]);
                acc[rt][ctp][3] = fmaf(kf[3], bfhi(p1), acc[rt][ctp][3]);
            }
        }
    }

    unsigned* cb0 = catp + (size_t)n * 96 * 16384 + h * 128;
#pragma unroll
    for (int rt = 0; rt < 3; ++rt) {
        const int combr = (tile0 + rt) * 16 + q * 4;
#pragma unroll
        for (int ctp = 0; ctp < 4; ++ctp) {
            const int px = w0 + ctp * 16 + col;
            unsigned v0 = (unsigned)f2bf(acc[rt][ctp][0]) |
                          ((unsigned)f2bf(acc[rt][ctp][1]) << 16);
            unsigned v1 = (unsigned)f2bf(acc[rt][ctp][2]) |
                          ((unsigned)f2bf(acc[rt][ctp][3]) << 16);
            cb0[(size_t)((combr >> 1) + 0) * 16384 + px] = v0;
            cb0[(size_t)((combr >> 1) + 1) * 16384 + px] = v1;
        }
    }
}

// Fuse conv v14: double-buffered Xt (69.6KB), ONE barrier per chunk.
// compute(c) on buf[c&1] overlaps: write buf[(c+1)&1] (data loaded 2 chunks
// ahead) + issue loads for c+2 + af pipeline continuous across chunks.
// Safety: chunk-start barrier guarantees all waves finished compute(c-1)'s
// reads of buf[(c+1)&1] before it is overwritten.
__global__ __launch_bounds__(256) void k_fuse_mfma(
    const unsigned* __restrict__ xp, const unsigned* __restrict__ catp,
    const unsigned short* __restrict__ fw3, const float* __restrict__ fuse_b,
    float* __restrict__ out)
{
    __shared__ __align__(16) unsigned Xt[2][4 * 32 * 68];  // 69632 B

    const int id = blockIdx.x;
    const int xcd = id & 7;
    const int unit = id >> 3;          // 0..63
    const int h0 = unit << 1;
    const int n  = xcd >> 1;
    const int w0 = (xcd & 1) << 6;

    const int t = threadIdx.x;
    const int lane = t & 63;
    const int ctp = t >> 6;            // wave-uniform px tile
    const int col = lane & 15, q = lane >> 4;

    int s_r[8], s_cp[8], s_li[8];
#pragma unroll
    for (int it = 0; it < 8; ++it) {
        int e = it * 256 + t;          // 2048 tasks: [r4][cp32][li16]
        s_r[it]  = e >> 9;
        s_cp[it] = (e >> 4) & 31;
        s_li[it] = e & 15;
    }
    const int hr = t >> 6, hcp = (t >> 1) & 31, hside = t & 1;
    const int hpx = hside ? (w0 + 64) : (w0 - 1);
    const bool hok = ((unsigned)hpx < 128u);

    const int bcol = ctp * 16 + col;
    const int m_kw[3] = { (bcol == 0) ? 64 : bcol - 1,
                          bcol,
                          (bcol == 63) ? 65 : bcol + 1 };

    f32x4 acc[2][4];                   // [row][rt]
#pragma unroll
    for (int row = 0; row < 2; ++row)
#pragma unroll
        for (int rt = 0; rt < 4; ++rt) acc[row][rt] = (f32x4){0.f, 0.f, 0.f, 0.f};

    const unsigned* csrc[4] = {
        nullptr,
        catp + (size_t)n * 96 * 16384,
        catp + ((size_t)n * 96 + 32) * 16384,
        catp + ((size_t)n * 96 + 64) * 16384 };

    // helper: af pointer for step index i (= g*2+ks) of a chunk
    auto afp = [&](int chunk, int i) -> const unsigned short* {
        const int g = i >> 1, ks = i & 1;
        return fw3 + ((size_t)((((g * 4 + chunk) * 2 + ks) * 4) * 64 + lane)) * 8;
    };

    // ---- prologue ----
    u32x4 pf[8];
    unsigned pfh;
    {   // chunk 0 from padded xp: unconditional loads
        const unsigned* src0 = xp + (size_t)n * 32 * XP_PS;
#pragma unroll
        for (int it = 0; it < 8; ++it)
            pf[it] = *(const u32x4*)(src0 + (size_t)s_cp[it] * XP_PS +
                                     (h0 + 4 + s_r[it]) * 144 + 8 + w0 + s_li[it] * 4);
        pfh = src0[(size_t)hcp * XP_PS + (h0 + 4 + hr) * 144 + 8 + hpx];
    }
    {   // write chunk 0 -> buf0
        unsigned* XW = &Xt[0][0];
#pragma unroll
        for (int it = 0; it < 8; ++it)
            *(u32x4*)(XW + (s_r[it] * 32 + s_cp[it]) * 68 + s_li[it] * 4) = pf[it];
        XW[(hr * 32 + hcp) * 68 + 64 + hside] = pfh;
    }
    {   // load chunk 1 -> pf
        const unsigned* src = csrc[1];
#pragma unroll
        for (int it = 0; it < 8; ++it) {
            int hh = h0 - 1 + s_r[it];
            u32x4 v = (u32x4){0u, 0u, 0u, 0u};
            if ((unsigned)hh < 128u)
                v = *(const u32x4*)(src + (size_t)s_cp[it] * 16384 + hh * 128 + w0 + s_li[it] * 4);
            pf[it] = v;
        }
        int hh = h0 - 1 + hr;
        unsigned v = 0u;
        if (hok && (unsigned)hh < 128u)
            v = src[(size_t)hcp * 16384 + hh * 128 + hpx];
        pfh = v;
    }
    // af preload: chunk 0 steps 0,1
    s16x8 afc[4], afn1[4];
    {
        const unsigned short* ap0 = afp(0, 0);
        const unsigned short* ap1 = afp(0, 1);
#pragma unroll
        for (int rt = 0; rt < 4; ++rt) {
            afc[rt]  = *(const s16x8*)(ap0 + (size_t)rt * 512);
            afn1[rt] = *(const s16x8*)(ap1 + (size_t)rt * 512);
        }
    }
    __syncthreads();   // buf0 ready; pf(chunk1) drained; af ready

#pragma unroll 1
    for (int chunk = 0; chunk < 4; ++chunk) {
        const unsigned* XB = &Xt[chunk & 1][0];

        // ---- write chunk+1's staged data into the other buffer ----
        if (chunk < 3) {
            unsigned* XW = &Xt[(chunk + 1) & 1][0];
#pragma unroll
            for (int it = 0; it < 8; ++it)
                *(u32x4*)(XW + (s_r[it] * 32 + s_cp[it]) * 68 + s_li[it] * 4) = pf[it];
            XW[(hr * 32 + hcp) * 68 + 64 + hside] = pfh;
        }

        // ---- issue loads for chunk+2 ----
        if (chunk < 2) {
            const unsigned* src = csrc[chunk + 2];
#pragma unroll
            for (int it = 0; it < 8; ++it) {
                int hh = h0 - 1 + s_r[it];
                u32x4 v = (u32x4){0u, 0u, 0u, 0u};
                if ((unsigned)hh < 128u)
                    v = *(const u32x4*)(src + (size_t)s_cp[it] * 16384 + hh * 128 + w0 + s_li[it] * 4);
                pf[it] = v;
            }
            int hh = h0 - 1 + hr;
            unsigned v = 0u;
            if (hok && (unsigned)hh < 128u)
                v = src[(size_t)hcp * 16384 + hh * 128 + hpx];
            pfh = v;
        }

        // ---- compute: 18 steps; af pipelined 2-deep, continuous across chunks
#pragma unroll
        for (int i = 0; i < 18; ++i) {
            const int g = i >> 1, ks = i & 1;
            const int kh = g / 3, kw = g % 3;

            s16x8 afn2[4];
            const bool ld2 = (i < 16) || (chunk < 3);
            if (ld2) {
                const unsigned short* ap = (i < 16) ? afp(chunk, i + 2)
                                                    : afp(chunk + 1, i - 16);
#pragma unroll
                for (int rt = 0; rt < 4; ++rt)
                    afn2[rt] = *(const s16x8*)(ap + (size_t)rt * 512);
            }

            const int cpb = ks * 16 + q * 4;
            const int mm = m_kw[kw];
            s16x8 bf[2];
#pragma unroll
            for (int row = 0; row < 2; ++row) {
                const unsigned* bp = XB + ((row + kh) * 32 + cpb) * 68 + mm;
                unsigned bb[4] = {bp[0], bp[68], bp[136], bp[204]};
                bf[row] = *(const s16x8*)bb;
            }
#pragma unroll
            for (int rt = 0; rt < 4; ++rt)
#pragma unroll
                for (int row = 0; row < 2; ++row)
                    acc[row][rt] = __builtin_amdgcn_mfma_f32_16x16x32_bf16(
                        afc[rt], bf[row], acc[row][rt], 0, 0, 0);

#pragma unroll
            for (int rt = 0; rt < 4; ++rt) {
                afc[rt] = afn1[rt];
                if (ld2) afn1[rt] = afn2[rt];
            }
        }
        __syncthreads();
    }

    const int px = w0 + ctp * 16 + col;
#pragma unroll
    for (int rt = 0; rt < 4; ++rt) {
        f32x4 fb = *(const f32x4*)(fuse_b + rt * 16 + q * 4);
#pragma unroll
        for (int row = 0; row < 2; ++row)
#pragma unroll
            for (int r = 0; r < 4; ++r) {
                int oc = rt * 16 + q * 4 + r;
                out[((size_t)n * 64 + oc) * 16384 + (h0 + row) * 128 + px] =
                    acc[row][rt][r] + fb[r];
            }
    }
}

extern "C" void kernel_launch(void* const* d_in, const int* in_sizes, int n_in,
                              void* d_out, int out_size, void* d_ws, size_t ws_size,
                              hipStream_t stream) {
    const float* x      = (const float*)d_in[0];
    const float* y      = (const float*)d_in[1];
    const float* gen_w  = (const float*)d_in[2];
    const float* gen_b  = (const float*)d_in[3];
    const float* fuse_w = (const float*)d_in[4];
    const float* fuse_b = (const float*)d_in[5];
    float* out = (float*)d_out;
    float* ws  = (float*)d_ws;

    unsigned* xp   = (unsigned*)(ws + OFF_XP);
    unsigned* catp = (unsigned*)(ws + OFF_CATP);

    k_prep<<<dim3(2653), dim3(256), 0, stream>>>(gen_w, gen_b, fuse_w, x, ws);
    k_gen_mfma<<<dim3(1024), dim3(256), 0, stream>>>(
        xp, y, (const unsigned short*)(ws + OFF_WPK), ws + OFF_GBP, catp);
    k_fuse_mfma<<<dim3(512), dim3(256), 0, stream>>>(
        xp, catp, (const unsigned short*)(ws + OFF_FW3), fuse_b, out);
}

// Round 24
// 71.805 us; speedup vs baseline: 1.2623x; 1.1008x over previous
//
#include <hip/hip_runtime.h>

// Problem: N=4, C=64, H=W=128, KS=3, dilations {1,3,5}
// x[4,64,128,128] f32, y[same], gen_w[1728,64], gen_b[1728],
// fuse_w[64,256,3,3], fuse_b[64] -> out[4,64,128,128] f32.

using f32x4 = __attribute__((ext_vector_type(4))) float;
using u32x4 = __attribute__((ext_vector_type(4))) unsigned;
using s16x8 = __attribute__((ext_vector_type(8))) short;

// Padded xp geometry: [plane][140 rows][144 cols], row = hh+5, col = ww+8.
#define XP_PS 20160        // plane stride in u32 (140*144)

// Workspace layout (float offsets)
#define OFF_WPK 0u         // gen_w A-frags bf16 [tap][tile12][ks2][lane][8] = 110592 bf16
#define OFF_FW3 55296u     // fuse_w A-frags bf16 [g][chunk][ks][rt][lane][8] = 147456 bf16
#define OFF_GBP 129024u    // gen_b fragment-order f32 [tap][tile12][row16]
#define OFF_XP  131072u    // x bf16-pairs u32, PADDED [n*32][140][144] = 2580480 u32
#define OFF_CATP 4325376u  // cat bf16-pairs u32 [n*96][16384]
// end 10616832 floats (~42.5 MB)

__device__ __forceinline__ unsigned short f2bf(float f) {
    unsigned u = __builtin_bit_cast(unsigned, f);
    u = (u + 0x7fffu + ((u >> 16) & 1u)) >> 16;   // RNE
    return (unsigned short)u;
}
__device__ __forceinline__ float bflo(unsigned p) {
    return __builtin_bit_cast(float, p << 16);
}
__device__ __forceinline__ float bfhi(unsigned p) {
    return __builtin_bit_cast(float, p & 0xffff0000u);
}

// ---- merged prep: blocks 0..53 wpk, 54..60 gb, 61..132 fw3, 133..2652 xp
__global__ void k_prep(const float* __restrict__ gen_w,
                       const float* __restrict__ gen_b,
                       const float* __restrict__ fuse_w,
                       const float* __restrict__ x,
                       float* __restrict__ ws) {
    int b = blockIdx.x;
    int t = threadIdx.x;
    if (b < 54) {                       // gen_w A-frags (16x16x32)
        int idx = b * 256 + t;
        if (idx >= 13824) return;
        unsigned short* wpk = (unsigned short*)(ws + OFF_WPK);
        int lane = idx & 63;
        int r = idx >> 6;
        int ks = r & 1; r >>= 1;
        int tile = r % 12, tap = r / 12;
        int comb = tile * 16 + (lane & 15);
        int cc0  = ks * 32 + (lane >> 4) * 8;
        const float* src = gen_w + (size_t)(comb * 9 + tap) * 64 + cc0;
        unsigned short v[8];
#pragma unroll
        for (int j = 0; j < 8; ++j) v[j] = f2bf(src[j]);
        *(s16x8*)(wpk + (size_t)idx * 8) = *(const s16x8*)v;
    } else if (b < 61) {                // gen_b fragment order
        int idx = (b - 54) * 256 + t;
        if (idx >= 1728) return;
        int row = idx & 15;
        int r = idx >> 4;
        int tile = r % 12, tap = r / 12;
        ws[OFF_GBP + idx] = gen_b[(tile * 16 + row) * 9 + tap];
    } else if (b < 133) {               // fuse_w A-frags (16x16x32)
        int idx = (b - 61) * 256 + t;
        if (idx >= 18432) return;
        unsigned short* fw3 = (unsigned short*)(ws + OFF_FW3);
        int lane = idx & 63;
        int f = idx >> 6;
        int rt = f & 3; f >>= 2;
        int ks = f & 1; f >>= 1;
        int chunk = f & 3;
        int g = f >> 2;
        int oc = rt * 16 + (lane & 15);
        int ic = chunk * 64 + ks * 32 + (lane >> 4) * 8;
        const float* src = fuse_w + (size_t)oc * 2304 + (size_t)ic * 9 + g;
        unsigned short v[8];
#pragma unroll
        for (int j = 0; j < 8; ++j) v[j] = f2bf(src[j * 9]);
        *(s16x8*)(fw3 + (size_t)idx * 8) = *(const s16x8*)v;
    } else {                            // x -> padded bf16-pair planes
        int idx = (b - 133) * 256 + t;  // 0..645119 (2520 blocks exactly)
        unsigned* xp = (unsigned*)(ws + OFF_XP);
        int plane = idx / 5040;         // 5040 u32x4 tasks per plane
        int rem   = idx % 5040;
        int row   = rem / 36;           // 0..139
        int c4    = rem % 36;           // 0..35 (u32x4 units)
        u32x4 v = (u32x4){0u, 0u, 0u, 0u};
        if (row >= 5 && row < 133 && c4 >= 2 && c4 < 34) {
            const float* sx = x + (size_t)(2 * plane) * 16384 +
                              (row - 5) * 128 + (c4 * 4 - 8);
            f32x4 v0 = *(const f32x4*)sx;
            f32x4 v1 = *(const f32x4*)(sx + 16384);
#pragma unroll
            for (int j = 0; j < 4; ++j)
                v[j] = (unsigned)f2bf(v0[j]) | ((unsigned)f2bf(v1[j]) << 16);
        }
        *(u32x4*)(xp + (size_t)plane * XP_PS + row * 144 + c4 * 4) = v;
    }
}

// XCD-contiguous decode for k_gen (1024 blocks)
__device__ __forceinline__ void decode_wu(int id, int& h, int& w0, int& n) {
    int wu = (id & 7) * 128 + (id >> 3);
    h = wu & 127;
    int sn = wu >> 7;
    w0 = (sn & 1) << 6;
    n = sn >> 1;
}

// MFMA kernel-generation + in-register depthwise apply (R19 + T5 setprio).
__global__ __launch_bounds__(256, 4) void k_gen_mfma(
    const unsigned* __restrict__ xp, const float* __restrict__ y,
    const unsigned short* __restrict__ wpk, const float* __restrict__ gbp,
    unsigned* __restrict__ catp)
{
    __shared__ __align__(16) unsigned Yt[2048];

    int h, w0, n;
    decode_wu(blockIdx.x, h, w0, n);
    const int t = threadIdx.x;
    const int lane = t & 63;
    const int wv = t >> 6;
    const int q = lane >> 4, col = lane & 15;

    {
        const float* yb = y + ((size_t)n * 64) * 16384 + h * 128 + w0 + lane;
#pragma unroll
        for (int p = 0; p < 8; ++p) {
            int cp = wv * 8 + p;
            float a = yb[(size_t)(2 * cp) * 16384];
            float b = yb[(size_t)(2 * cp + 1) * 16384];
            unsigned v = (unsigned)f2bf(a) | ((unsigned)f2bf(b) << 16);
            Yt[(unsigned)(lane * 32 + cp) ^ (((unsigned)(lane & 7)) << 2)] = v;
        }
    }
    __syncthreads();

    s16x8 bfr[4][2];
#pragma unroll
    for (int ctp = 0; ctp < 4; ++ctp)
#pragma unroll
        for (int ks = 0; ks < 2; ++ks) {
            int px = ctp * 16 + col;
            unsigned word = ((unsigned)(px * 32 + ks * 16 + q * 4)) ^
                            (((unsigned)(px & 7)) << 2);
            bfr[ctp][ks] = *(const s16x8*)(Yt + word);
        }

    const int tile0 = wv * 3;
    const unsigned* xn = xp + (size_t)n * 32 * XP_PS;

    float acc[3][4][4];
#pragma unroll
    for (int rt = 0; rt < 3; ++rt)
#pragma unroll
        for (int ctp = 0; ctp < 4; ++ctp)
#pragma unroll
            for (int r = 0; r < 4; ++r) acc[rt][ctp][r] = 0.f;

#pragma unroll 1
    for (int tap = 0; tap < 9; ++tap) {
        const int ti = tap / 3, tj = tap % 3;
        const unsigned short* wp = wpk + ((size_t)(tap * 12 + tile0) * 2 * 64 + lane) * 8;
        __builtin_amdgcn_s_setprio(1);
#pragma unroll
        for (int rt = 0; rt < 3; ++rt) {
            const int tile = tile0 + rt;
            const int bi = tile >> 2;
            const int d  = 2 * bi + 1;
            const int hh = h + (ti - 1) * d;
            const int cb = (tile & 3) * 16 + q * 4;

            f32x4 cinit = *(const f32x4*)(gbp + (size_t)(tap * 12 + tile) * 16 + q * 4);
            s16x8 a0 = *(const s16x8*)(wp + (size_t)(rt * 2 + 0) * 512);
            s16x8 a1 = *(const s16x8*)(wp + (size_t)(rt * 2 + 1) * 512);
#pragma unroll
            for (int ctp = 0; ctp < 4; ++ctp) {
                f32x4 kf = __builtin_amdgcn_mfma_f32_16x16x32_bf16(a0, bfr[ctp][0], cinit, 0, 0, 0);
                kf = __builtin_amdgcn_mfma_f32_16x16x32_bf16(a1, bfr[ctp][1], kf, 0, 0, 0);
                const int ww = w0 + ctp * 16 + col + (tj - 1) * d;
                const unsigned* xr = xn + (size_t)(cb >> 1) * XP_PS +
                                     (hh + 5) * 144 + (ww + 8);
                unsigned p0 = xr[0];
                unsigned p1 = xr[XP_PS];
                acc[rt][ctp][0] = fmaf(kf[0], bflo(p0), acc[rt][ctp][0]);
                acc[rt][ctp][1] = fmaf(kf[1], bfhi(p0), acc[rt][ctp][1]);
                acc[rt][ctp][2] = fmaf(kf[2], bflo(p1), acc[rt][ctp][2]);
                acc[rt][ctp][3] = fmaf(kf[3], bfhi(p1), acc[rt][ctp][3]);
            }
        }
        __builtin_amdgcn_s_setprio(0);
    }

    unsigned* cb0 = catp + (size_t)n * 96 * 16384 + h * 128;
#pragma unroll
    for (int rt = 0; rt < 3; ++rt) {
        const int combr = (tile0 + rt) * 16 + q * 4;
#pragma unroll
        for (int ctp = 0; ctp < 4; ++ctp) {
            const int px = w0 + ctp * 16 + col;
            unsigned v0 = (unsigned)f2bf(acc[rt][ctp][0]) |
                          ((unsigned)f2bf(acc[rt][ctp][1]) << 16);
            unsigned v1 = (unsigned)f2bf(acc[rt][ctp][2]) |
                          ((unsigned)f2bf(acc[rt][ctp][3]) << 16);
            cb0[(size_t)((combr >> 1) + 0) * 16384 + px] = v0;
            cb0[(size_t)((combr >> 1) + 1) * 16384 + px] = v1;
        }
    }
}

// Fuse conv v15: R23 double-buffered single-barrier structure + T5 setprio
// around the per-step MFMA cluster.
__global__ __launch_bounds__(256) void k_fuse_mfma(
    const unsigned* __restrict__ xp, const unsigned* __restrict__ catp,
    const unsigned short* __restrict__ fw3, const float* __restrict__ fuse_b,
    float* __restrict__ out)
{
    __shared__ __align__(16) unsigned Xt[2][4 * 32 * 68];  // 69632 B

    const int id = blockIdx.x;
    const int xcd = id & 7;
    const int unit = id >> 3;          // 0..63
    const int h0 = unit << 1;
    const int n  = xcd >> 1;
    const int w0 = (xcd & 1) << 6;

    const int t = threadIdx.x;
    const int lane = t & 63;
    const int ctp = t >> 6;            // wave-uniform px tile
    const int col = lane & 15, q = lane >> 4;

    int s_r[8], s_cp[8], s_li[8];
#pragma unroll
    for (int it = 0; it < 8; ++it) {
        int e = it * 256 + t;          // 2048 tasks: [r4][cp32][li16]
        s_r[it]  = e >> 9;
        s_cp[it] = (e >> 4) & 31;
        s_li[it] = e & 15;
    }
    const int hr = t >> 6, hcp = (t >> 1) & 31, hside = t & 1;
    const int hpx = hside ? (w0 + 64) : (w0 - 1);
    const bool hok = ((unsigned)hpx < 128u);

    const int bcol = ctp * 16 + col;
    const int m_kw[3] = { (bcol == 0) ? 64 : bcol - 1,
                          bcol,
                          (bcol == 63) ? 65 : bcol + 1 };

    f32x4 acc[2][4];                   // [row][rt]
#pragma unroll
    for (int row = 0; row < 2; ++row)
#pragma unroll
        for (int rt = 0; rt < 4; ++rt) acc[row][rt] = (f32x4){0.f, 0.f, 0.f, 0.f};

    const unsigned* csrc[4] = {
        nullptr,
        catp + (size_t)n * 96 * 16384,
        catp + ((size_t)n * 96 + 32) * 16384,
        catp + ((size_t)n * 96 + 64) * 16384 };

    auto afp = [&](int chunk, int i) -> const unsigned short* {
        const int g = i >> 1, ks = i & 1;
        return fw3 + ((size_t)((((g * 4 + chunk) * 2 + ks) * 4) * 64 + lane)) * 8;
    };

    // ---- prologue ----
    u32x4 pf[8];
    unsigned pfh;
    {   // chunk 0 from padded xp: unconditional loads
        const unsigned* src0 = xp + (size_t)n * 32 * XP_PS;
#pragma unroll
        for (int it = 0; it < 8; ++it)
            pf[it] = *(const u32x4*)(src0 + (size_t)s_cp[it] * XP_PS +
                                     (h0 + 4 + s_r[it]) * 144 + 8 + w0 + s_li[it] * 4);
        pfh = src0[(size_t)hcp * XP_PS + (h0 + 4 + hr) * 144 + 8 + hpx];
    }
    {   // write chunk 0 -> buf0
        unsigned* XW = &Xt[0][0];
#pragma unroll
        for (int it = 0; it < 8; ++it)
            *(u32x4*)(XW + (s_r[it] * 32 + s_cp[it]) * 68 + s_li[it] * 4) = pf[it];
        XW[(hr * 32 + hcp) * 68 + 64 + hside] = pfh;
    }
    {   // load chunk 1 -> pf
        const unsigned* src = csrc[1];
#pragma unroll
        for (int it = 0; it < 8; ++it) {
            int hh = h0 - 1 + s_r[it];
            u32x4 v = (u32x4){0u, 0u, 0u, 0u};
            if ((unsigned)hh < 128u)
                v = *(const u32x4*)(src + (size_t)s_cp[it] * 16384 + hh * 128 + w0 + s_li[it] * 4);
            pf[it] = v;
        }
        int hh = h0 - 1 + hr;
        unsigned v = 0u;
        if (hok && (unsigned)hh < 128u)
            v = src[(size_t)hcp * 16384 + hh * 128 + hpx];
        pfh = v;
    }
    s16x8 afc[4], afn1[4];
    {
        const unsigned short* ap0 = afp(0, 0);
        const unsigned short* ap1 = afp(0, 1);
#pragma unroll
        for (int rt = 0; rt < 4; ++rt) {
            afc[rt]  = *(const s16x8*)(ap0 + (size_t)rt * 512);
            afn1[rt] = *(const s16x8*)(ap1 + (size_t)rt * 512);
        }
    }
    __syncthreads();   // buf0 ready; pf(chunk1) drained; af ready

#pragma unroll 1
    for (int chunk = 0; chunk < 4; ++chunk) {
        const unsigned* XB = &Xt[chunk & 1][0];

        // ---- write chunk+1's staged data into the other buffer ----
        if (chunk < 3) {
            unsigned* XW = &Xt[(chunk + 1) & 1][0];
#pragma unroll
            for (int it = 0; it < 8; ++it)
                *(u32x4*)(XW + (s_r[it] * 32 + s_cp[it]) * 68 + s_li[it] * 4) = pf[it];
            XW[(hr * 32 + hcp) * 68 + 64 + hside] = pfh;
        }

        // ---- issue loads for chunk+2 ----
        if (chunk < 2) {
            const unsigned* src = csrc[chunk + 2];
#pragma unroll
            for (int it = 0; it < 8; ++it) {
                int hh = h0 - 1 + s_r[it];
                u32x4 v = (u32x4){0u, 0u, 0u, 0u};
                if ((unsigned)hh < 128u)
                    v = *(const u32x4*)(src + (size_t)s_cp[it] * 16384 + hh * 128 + w0 + s_li[it] * 4);
                pf[it] = v;
            }
            int hh = h0 - 1 + hr;
            unsigned v = 0u;
            if (hok && (unsigned)hh < 128u)
                v = src[(size_t)hcp * 16384 + hh * 128 + hpx];
            pfh = v;
        }

        // ---- compute: 18 steps; af 2-deep, continuous across chunks ----
#pragma unroll
        for (int i = 0; i < 18; ++i) {
            const int g = i >> 1, ks = i & 1;
            const int kh = g / 3, kw = g % 3;

            s16x8 afn2[4];
            const bool ld2 = (i < 16) || (chunk < 3);
            if (ld2) {
                const unsigned short* ap = (i < 16) ? afp(chunk, i + 2)
                                                    : afp(chunk + 1, i - 16);
#pragma unroll
                for (int rt = 0; rt < 4; ++rt)
                    afn2[rt] = *(const s16x8*)(ap + (size_t)rt * 512);
            }

            const int cpb = ks * 16 + q * 4;
            const int mm = m_kw[kw];
            s16x8 bf[2];
#pragma unroll
            for (int row = 0; row < 2; ++row) {
                const unsigned* bp = XB + ((row + kh) * 32 + cpb) * 68 + mm;
                unsigned bb[4] = {bp[0], bp[68], bp[136], bp[204]};
                bf[row] = *(const s16x8*)bb;
            }
            __builtin_amdgcn_s_setprio(1);
#pragma unroll
            for (int rt = 0; rt < 4; ++rt)
#pragma unroll
                for (int row = 0; row < 2; ++row)
                    acc[row][rt] = __builtin_amdgcn_mfma_f32_16x16x32_bf16(
                        afc[rt], bf[row], acc[row][rt], 0, 0, 0);
            __builtin_amdgcn_s_setprio(0);

#pragma unroll
            for (int rt = 0; rt < 4; ++rt) {
                afc[rt] = afn1[rt];
                if (ld2) afn1[rt] = afn2[rt];
            }
        }
        __syncthreads();
    }

    const int px = w0 + ctp * 16 + col;
#pragma unroll
    for (int rt = 0; rt < 4; ++rt) {
        f32x4 fb = *(const f32x4*)(fuse_b + rt * 16 + q * 4);
#pragma unroll
        for (int row = 0; row < 2; ++row)
#pragma unroll
            for (int r = 0; r < 4; ++r) {
                int oc = rt * 16 + q * 4 + r;
                out[((size_t)n * 64 + oc) * 16384 + (h0 + row) * 128 + px] =
                    acc[row][rt][r] + fb[r];
            }
    }
}

extern "C" void kernel_launch(void* const* d_in, const int* in_sizes, int n_in,
                              void* d_out, int out_size, void* d_ws, size_t ws_size,
                              hipStream_t stream) {
    const float* x      = (const float*)d_in[0];
    const float* y      = (const float*)d_in[1];
    const float* gen_w  = (const float*)d_in[2];
    const float* gen_b  = (const float*)d_in[3];
    const float* fuse_w = (const float*)d_in[4];
    const float* fuse_b = (const float*)d_in[5];
    float* out = (float*)d_out;
    float* ws  = (float*)d_ws;

    unsigned* xp   = (unsigned*)(ws + OFF_XP);
    unsigned* catp = (unsigned*)(ws + OFF_CATP);

    k_prep<<<dim3(2653), dim3(256), 0, stream>>>(gen_w, gen_b, fuse_w, x, ws);
    k_gen_mfma<<<dim3(1024), dim3(256), 0, stream>>>(
        xp, y, (const unsigned short*)(ws + OFF_WPK), ws + OFF_GBP, catp);
    k_fuse_mfma<<<dim3(512), dim3(256), 0, stream>>>(
        xp, catp, (const unsigned short*)(ws + OFF_FW3), fuse_b, out);
}